// Round 2
// 525.899 us; speedup vs baseline: 1.0181x; 1.0181x over previous
//
#include <hip/hip_runtime.h>

#define NSTEP 730
#define NGRID 10000
#define DPF 10   // 730 = 73 chunks of 10; ping-pong pairs: 36*2 + 1 tail

__global__ __launch_bounds__(64, 1) void hbv_kernel(
    const float* __restrict__ x, const float* __restrict__ params,
    float* __restrict__ out)
{
    const int g = blockIdx.x * 64 + threadIdx.x;
    if (g >= NGRID) return;

    // parameters[-1]: last timestep slice, shape (NGRID, 12, 1)
    const unsigned pbase = (unsigned)((NSTEP - 1) * NGRID + g) * 12u;
    float pr[12];
#pragma unroll
    for (int i = 0; i < 12; ++i) pr[i] = params[pbase + i];

    const float lo[12] = {1.0f, 50.0f, 0.05f, 0.01f, 0.001f, 0.2f, 0.0f, 0.0f, -2.5f, 0.5f, 0.0f, 0.0f};
    const float hi[12] = {6.0f, 1000.0f, 0.9f, 0.5f, 0.2f, 1.0f, 10.0f, 100.0f, 2.5f, 10.0f, 0.1f, 0.2f};
    float ps[12];
#pragma unroll
    for (int i = 0; i < 12; ++i) ps[i] = lo[i] + pr[i] * (hi[i] - lo[i]);

    const float BETA = ps[0], FC = ps[1], K0 = ps[2], K1 = ps[3], K2 = ps[4], LP = ps[5],
                PERCmax = ps[6], UZL = ps[7], TT = ps[8], CFMAX = ps[9], CFR = ps[10], CWH = ps[11];

    const float rFC   = 1.0f / FC;
    const float rLPFC = 1.0f / (LP * FC);
    const float nCFR  = -CFR;          // refreeze arg = CFR*CFMAX*(TT-Tt) = nCFR * (CFMAX*(Tt-TT))
    const float omK1  = 1.0f - K1;
    const float omK2  = 1.0f - K2;

    float SNOWPACK = 0.001f, MELTWATER = 0.001f, SM = 0.001f, SUZ = 0.001f, SLZ = 0.001f;

    // uniform SGPR bases + 32-bit running element offsets (saddr + u32 voffset form)
    float* __restrict__ const outQ = out;
    float* __restrict__ const outE = out + (unsigned)(NSTEP * NGRID);
    float* __restrict__ const outS = out + 2u * (unsigned)(NSTEP * NGRID);

    unsigned pfOff = (unsigned)g * 3u;   // element offset into x of next prefetch chunk
    unsigned stOff = (unsigned)g;        // element offset into each out stream

#define PF(P_, T_, E_) do {                                                  \
    _Pragma("unroll")                                                        \
    for (int d = 0; d < DPF; ++d) {                                          \
        const unsigned o_ = pfOff + (unsigned)(d * 3 * NGRID);               \
        P_[d] = x[o_]; T_[d] = x[o_ + 1u]; E_[d] = x[o_ + 2u];               \
    }                                                                        \
    pfOff += (unsigned)(DPF * 3 * NGRID);                                    \
} while (0)

#define CHUNK(P_, T_, E_) do {                                               \
    _Pragma("unroll")                                                        \
    for (int d = 0; d < DPF; ++d) {                                          \
        const float Pt = P_[d], Tt = T_[d], PETt = E_[d];                    \
        const float dT   = Tt - TT;                                          \
        const float RAIN = (dT >= 0.0f) ? Pt : 0.0f;                         \
        SNOWPACK += Pt - RAIN;                                               \
        const float m0   = CFMAX * dT;                                       \
        const float melt = fminf(fmaxf(m0, 0.0f), SNOWPACK);                 \
        MELTWATER += melt;                                                   \
        SNOWPACK  -= melt;                                                   \
        const float refreeze = fminf(fmaxf(nCFR * m0, 0.0f), MELTWATER);     \
        SNOWPACK  += refreeze;                                               \
        MELTWATER -= refreeze;                                               \
        const float tosoil = fmaxf(MELTWATER - CWH * SNOWPACK, 0.0f);        \
        MELTWATER -= tosoil;                                                 \
        /* sw = clip((SM/FC)^BETA, 0, 1); exp2>=0 so low clamp is dead.   */ \
        /* SM CAN exceed FC (excess is never removed) -> keep min(,1).    */ \
        const float sw = fminf(                                              \
            __builtin_amdgcn_exp2f(BETA * __builtin_amdgcn_logf(SM * rFC)),  \
            1.0f);                                                           \
        const float rt       = RAIN + tosoil;                                \
        const float recharge = rt * sw;                                      \
        SM += rt - recharge;                                                 \
        const float excess = fmaxf(SM - FC, 0.0f);                           \
        const float evapf  = fminf(SM * rLPFC, 1.0f); /* SM>0: low clamp dead */ \
        const float ETact  = fminf(SM, PETt * evapf);                        \
        SM = fmaxf(SM - ETact, 1e-5f);                                       \
        SUZ += recharge + excess;                                            \
        const float PERC = fminf(SUZ, PERCmax);                              \
        SUZ -= PERC;                                                         \
        const float Q0   = K0 * fmaxf(SUZ - UZL, 0.0f);                      \
        const float suz1 = SUZ - Q0;                                         \
        const float Q1   = K1 * suz1;                                        \
        SUZ = omK1 * suz1;            /* == suz1 - Q1, independent muls */   \
        const float t2 = SLZ + PERC;                                         \
        const float Q2 = K2 * t2;                                            \
        SLZ = omK2 * t2;              /* == t2 - Q2, independent muls   */   \
        outQ[stOff] = (Q0 + Q1) + Q2;                                        \
        outE[stOff] = ETact;                                                 \
        outS[stOff] = SNOWPACK;                                              \
        stOff += (unsigned)NGRID;                                            \
    }                                                                        \
} while (0)

    // ---- ping-pong double-buffered pipeline: no register rotate, no tail clamp ----
    float aP[DPF], aT[DPF], aE[DPF];
    float bP[DPF], bT[DPF], bE[DPF];

    PF(aP, aT, aE);                       // chunk 0

#pragma unroll 1
    for (int c = 0; c < 72; c += 2) {
        PF(bP, bT, bE);                   // chunk c+1 (loads fly under A's compute)
        CHUNK(aP, aT, aE);                // chunk c
        PF(aP, aT, aE);                   // chunk c+2 (loads fly under B's compute)
        CHUNK(bP, bT, bE);                // chunk c+1
    }
    CHUNK(aP, aT, aE);                    // chunk 72 (already prefetched, no PF)

#undef PF
#undef CHUNK
}

extern "C" void kernel_launch(void* const* d_in, const int* in_sizes, int n_in,
                              void* d_out, int out_size, void* d_ws, size_t ws_size,
                              hipStream_t stream) {
    const float* x = (const float*)d_in[0];
    const float* params = (const float*)d_in[1];
    float* out = (float*)d_out;
    const int threads = 64;
    const int blocks = (NGRID + threads - 1) / threads;  // 157 blocks, 1 wave each
    hbv_kernel<<<blocks, threads, 0, stream>>>(x, params, out);
}